// Round 1
// baseline (477.972 us; speedup 1.0000x reference)
//
#include <hip/hip_runtime.h>

typedef short  short8  __attribute__((ext_vector_type(8)));
typedef float  floatx4 __attribute__((ext_vector_type(4)));

#define TT 512
#define DD 32
#define HH 128
#define AA 10

__device__ __forceinline__ unsigned f2bf(float f) {
    unsigned u = __builtin_bit_cast(unsigned, f);
    return (u + 0x7fffu + ((u >> 16) & 1u)) >> 16;   // RNE f32 -> bf16
}

__device__ __forceinline__ short8 cvt8(floatx4 a, floatx4 b) {
    short8 r;
    r[0] = (short)f2bf(a[0]); r[1] = (short)f2bf(a[1]);
    r[2] = (short)f2bf(a[2]); r[3] = (short)f2bf(a[3]);
    r[4] = (short)f2bf(b[0]); r[5] = (short)f2bf(b[1]);
    r[6] = (short)f2bf(b[2]); r[7] = (short)f2bf(b[3]);
    return r;
}

__device__ __forceinline__ float fsig(float x) {
    return __builtin_amdgcn_rcpf(1.0f + __expf(-x));
}
__device__ __forceinline__ float ftanh(float x) {
    // tanh(x) = 1 - 2/(1+e^{2x}); robust at +-inf
    return 1.0f - 2.0f * __builtin_amdgcn_rcpf(1.0f + __expf(2.0f * x));
}

// One block = 16 batch rows, full T loop, no inter-block sync.
// gates^T = [W_hh | W_ih] @ [h ; x]^T  (M=512 gates, N=16 batch, K=160)
// A-frags (weights) live in registers for the whole kernel.
__global__ __launch_bounds__(512, 2)
void lstm_fused(const float* __restrict__ x,    const float* __restrict__ W_ih,
                const float* __restrict__ W_hh, const float* __restrict__ b_ih,
                const float* __restrict__ b_hh, const float* __restrict__ fc_w,
                const float* __restrict__ fc_b, float* __restrict__ out)
{
    __shared__ unsigned short h_lds[2][16 * HH];   // bf16 h, XOR-swizzled, double buffered
    __shared__ float hq[16][HH + 4];               // final h (f32) for the fc epilogue

    const int tid  = threadIdx.x;
    const int lane = tid & 63;
    const int w    = tid >> 6;      // wave 0..7
    const int l15  = lane & 15;     // A-row within tile / B-col (batch) / D-col (batch)
    const int lgrp = lane >> 4;     // k-group 0..3

    const long bglob = (long)blockIdx.x * 16 + l15;

    // ---- resident A-fragments of [W_hh | W_ih] (bf16) + bias ----
    // wave w owns tiles {w, w+8, w+16, w+24} = i/f/g/o rows for j in [16w,16w+16)
    short8 afr[4][5];
    float  bias[4][4];
    #pragma unroll
    for (int tg = 0; tg < 4; ++tg) {
        const int m  = w + 8 * tg;
        const int ga = 16 * m + l15;                 // A-frag gate row for this lane
        #pragma unroll
        for (int s = 0; s < 4; ++s) {                // K slices 0..127 -> W_hh
            const float* p = W_hh + ga * HH + 32 * s + 8 * lgrp;
            afr[tg][s] = cvt8(*(const floatx4*)p, *(const floatx4*)(p + 4));
        }
        {                                            // K slice 128..159 -> W_ih
            const float* p = W_ih + ga * DD + 8 * lgrp;
            afr[tg][4] = cvt8(*(const floatx4*)p, *(const floatx4*)(p + 4));
        }
        #pragma unroll
        for (int r = 0; r < 4; ++r) {                // D-layout row = 4*lgrp + r
            const int gd = 16 * m + 4 * lgrp + r;
            bias[tg][r] = b_ih[gd] + b_hh[gd];
        }
    }

    // zero both h buffers (h0 = 0)
    for (int i = tid; i < 2 * 16 * HH / 2; i += 512) ((unsigned*)h_lds)[i] = 0u;
    __syncthreads();

    // x B-frag prefetch for t=0: lane reads x[b][t][8*lgrp .. +7] (32 B)
    {
        const float* xp = x + (bglob * TT + 0) * DD + 8 * lgrp;
        // fallthrough into loop-carried registers below
    }
    floatx4 xa = *(const floatx4*)(x + (bglob * TT) * DD + 8 * lgrp);
    floatx4 xb = *(const floatx4*)(x + (bglob * TT) * DD + 8 * lgrp + 4);

    float c[4]   = {0.f, 0.f, 0.f, 0.f};
    float hreg[4] = {0.f, 0.f, 0.f, 0.f};
    const int j0     = 16 * w + 4 * lgrp;                               // 4 consecutive j per lane
    const int wr_off = (l15 * 256 + 2 * j0) ^ ((l15 & 7) << 4);         // swizzled h write addr

    int cur = 0;
    for (int t = 0; t < TT; ++t) {
        // convert current x frag, then prefetch next step's x
        short8 xf = cvt8(xa, xb);
        {
            const int tn = (t + 1 < TT) ? (t + 1) : (TT - 1);
            const float* xp = x + (bglob * TT + tn) * DD + 8 * lgrp;
            xa = *(const floatx4*)(xp);
            xb = *(const floatx4*)(xp + 4);
        }

        // h B-frags from LDS (swizzled): lane needs h[b][32s + 8*lgrp .. +7]
        short8 hb[4];
        const char* hbase = (const char*)h_lds[cur];
        #pragma unroll
        for (int s = 0; s < 4; ++s) {
            const int off = (l15 * 256 + 64 * s + 16 * lgrp) ^ ((l15 & 7) << 4);
            hb[s] = *(const short8*)(hbase + off);
        }

        // gates = bias + W_hh@h + W_ih@x   (acc initialized with bias)
        floatx4 acc[4];
        #pragma unroll
        for (int tg = 0; tg < 4; ++tg)
            acc[tg] = (floatx4){bias[tg][0], bias[tg][1], bias[tg][2], bias[tg][3]};
        #pragma unroll
        for (int s = 0; s < 4; ++s)
            #pragma unroll
            for (int tg = 0; tg < 4; ++tg)
                acc[tg] = __builtin_amdgcn_mfma_f32_16x16x32_bf16(afr[tg][s], hb[s], acc[tg], 0, 0, 0);
        #pragma unroll
        for (int tg = 0; tg < 4; ++tg)
            acc[tg] = __builtin_amdgcn_mfma_f32_16x16x32_bf16(afr[tg][4], xf, acc[tg], 0, 0, 0);

        // lane-local i/f/g/o quad -> c,h update (b = l15, j = j0 + r)
        #pragma unroll
        for (int r = 0; r < 4; ++r) {
            const float iv = fsig(acc[0][r]);
            const float fv = fsig(acc[1][r]);
            const float gv = ftanh(acc[2][r]);
            const float ov = fsig(acc[3][r]);
            const float cn = fv * c[r] + iv * gv;
            c[r]    = cn;
            hreg[r] = ov * ftanh(cn);
        }

        // write h_new (bf16) to the other buffer; one barrier per step
        {
            unsigned u0 = f2bf(hreg[0]) | (f2bf(hreg[1]) << 16);
            unsigned u1 = f2bf(hreg[2]) | (f2bf(hreg[3]) << 16);
            uint2 uv; uv.x = u0; uv.y = u1;
            *(uint2*)((char*)h_lds[cur ^ 1] + wr_off) = uv;
        }
        __syncthreads();
        cur ^= 1;
    }

    // ---- epilogue: h_n, c_n, q = h @ fc_w^T + fc_b ----
    {
        floatx4 hv = {hreg[0], hreg[1], hreg[2], hreg[3]};
        floatx4 cv = {c[0], c[1], c[2], c[3]};
        *(floatx4*)(out + 10240 + bglob * HH + j0)          = hv;  // h_n
        *(floatx4*)(out + 10240 + 131072 + bglob * HH + j0) = cv;  // c_n
        hq[l15][j0 + 0] = hreg[0]; hq[l15][j0 + 1] = hreg[1];
        hq[l15][j0 + 2] = hreg[2]; hq[l15][j0 + 3] = hreg[3];
    }
    __syncthreads();
    if (tid < 16 * AA) {
        const int b = tid / AA, a = tid - AA * b;
        float s = fc_b[a];
        const float* fw = fc_w + a * HH;
        const float* hr = &hq[b][0];
        #pragma unroll 8
        for (int j = 0; j < HH; ++j) s = fmaf(hr[j], fw[j], s);
        out[((long)blockIdx.x * 16 + b) * AA + a] = s;
    }
}

extern "C" void kernel_launch(void* const* d_in, const int* in_sizes, int n_in,
                              void* d_out, int out_size, void* d_ws, size_t ws_size,
                              hipStream_t stream) {
    const float* x    = (const float*)d_in[0];
    const float* W_ih = (const float*)d_in[1];
    const float* W_hh = (const float*)d_in[2];
    const float* b_ih = (const float*)d_in[3];
    const float* b_hh = (const float*)d_in[4];
    const float* fc_w = (const float*)d_in[5];
    const float* fc_b = (const float*)d_in[6];
    lstm_fused<<<dim3(1024 / 16), dim3(512), 0, stream>>>(
        x, W_ih, W_hh, b_ih, b_hh, fc_w, fc_b, (float*)d_out);
}

// Round 2
// 465.911 us; speedup vs baseline: 1.0259x; 1.0259x over previous
//
#include <hip/hip_runtime.h>

typedef short  short8  __attribute__((ext_vector_type(8)));
typedef float  floatx4 __attribute__((ext_vector_type(4)));

#define TT 512
#define DD 32
#define HH 128
#define AA 10

__device__ __forceinline__ unsigned f2bf(float f) {
    unsigned u = __builtin_bit_cast(unsigned, f);
    return (u + 0x7fffu + ((u >> 16) & 1u)) >> 16;   // RNE f32 -> bf16
}

__device__ __forceinline__ short8 cvt8(floatx4 a, floatx4 b) {
    short8 r;
    r[0] = (short)f2bf(a[0]); r[1] = (short)f2bf(a[1]);
    r[2] = (short)f2bf(a[2]); r[3] = (short)f2bf(a[3]);
    r[4] = (short)f2bf(b[0]); r[5] = (short)f2bf(b[1]);
    r[6] = (short)f2bf(b[2]); r[7] = (short)f2bf(b[3]);
    return r;
}

__device__ __forceinline__ float fsig(float x) {
    return __builtin_amdgcn_rcpf(1.0f + __expf(-x));
}
__device__ __forceinline__ float ftanh(float x) {
    return 1.0f - 2.0f * __builtin_amdgcn_rcpf(1.0f + __expf(2.0f * x));
}

// Step barrier WITHOUT the vmcnt(0) drain __syncthreads() would emit:
// only LDS ops must be visible across the barrier; in-flight global x
// prefetch loads may float across (they are consumed a full step later).
__device__ __forceinline__ void step_barrier() {
    asm volatile("s_waitcnt lgkmcnt(0)" ::: "memory");
    __builtin_amdgcn_s_barrier();
    asm volatile("" ::: "memory");
}

// One block = 16 batch rows, full T loop, no inter-block sync.
// gates^T = [W_hh | W_ih] @ [h ; x]^T  (M=512 gates, N=16 batch, K=160)
// A-frags (weights) live in registers for the whole kernel.
__global__ __launch_bounds__(512, 2)
void lstm_fused(const float* __restrict__ x,    const float* __restrict__ W_ih,
                const float* __restrict__ W_hh, const float* __restrict__ b_ih,
                const float* __restrict__ b_hh, const float* __restrict__ fc_w,
                const float* __restrict__ fc_b, float* __restrict__ out)
{
    __shared__ unsigned short h_lds[2][16 * HH];   // bf16 h, XOR-swizzled, double buffered
    __shared__ float hq[16][HH + 4];               // final h (f32) for the fc epilogue

    const int tid  = threadIdx.x;
    const int lane = tid & 63;
    const int w    = tid >> 6;      // wave 0..7
    const int l15  = lane & 15;     // A-row within tile / B-col (batch) / D-col (batch)
    const int lgrp = lane >> 4;     // k-group 0..3

    const long bglob = (long)blockIdx.x * 16 + l15;

    // ---- resident A-fragments of [W_hh | W_ih] (bf16) + bias ----
    // wave w owns tiles {w, w+8, w+16, w+24} = i/f/g/o rows for j in [16w,16w+16)
    short8 afr[4][5];
    float  bias[4][4];
    #pragma unroll
    for (int tg = 0; tg < 4; ++tg) {
        const int m  = w + 8 * tg;
        const int ga = 16 * m + l15;                 // A-frag gate row for this lane
        #pragma unroll
        for (int s = 0; s < 4; ++s) {                // K slices 0..127 -> W_hh
            const float* p = W_hh + ga * HH + 32 * s + 8 * lgrp;
            afr[tg][s] = cvt8(*(const floatx4*)p, *(const floatx4*)(p + 4));
        }
        {                                            // K slice 128..159 -> W_ih
            const float* p = W_ih + ga * DD + 8 * lgrp;
            afr[tg][4] = cvt8(*(const floatx4*)p, *(const floatx4*)(p + 4));
        }
        #pragma unroll
        for (int r = 0; r < 4; ++r) {                // D-layout row = 4*lgrp + r
            const int gd = 16 * m + 4 * lgrp + r;
            bias[tg][r] = b_ih[gd] + b_hh[gd];
        }
    }

    // zero both h buffers (h0 = 0)
    for (int i = tid; i < 2 * 16 * HH / 2; i += 512) ((unsigned*)h_lds)[i] = 0u;
    __syncthreads();

    // x prefetch for t=0
    floatx4 xa = *(const floatx4*)(x + (bglob * TT) * DD + 8 * lgrp);
    floatx4 xb = *(const floatx4*)(x + (bglob * TT) * DD + 8 * lgrp + 4);

    float c[4]    = {0.f, 0.f, 0.f, 0.f};
    float hreg[4] = {0.f, 0.f, 0.f, 0.f};
    const int j0     = 16 * w + 4 * lgrp;                               // 4 consecutive j per lane
    const int wr_off = (l15 * 256 + 2 * j0) ^ ((l15 & 7) << 4);         // swizzled h write addr

    int cur = 0;
    for (int t = 0; t < TT; ++t) {
        // convert current x frag, then prefetch next step's x (never drained
        // at the step barrier -- full step of latency cover)
        short8 xf = cvt8(xa, xb);
        {
            const int tn = (t + 1 < TT) ? (t + 1) : (TT - 1);
            const float* xp = x + (bglob * TT + tn) * DD + 8 * lgrp;
            xa = *(const floatx4*)(xp);
            xb = *(const floatx4*)(xp + 4);
        }

        // h B-frags from LDS (swizzled): lane needs h[b][32s + 8*lgrp .. +7]
        short8 hb[4];
        const char* hbase = (const char*)h_lds[cur];
        #pragma unroll
        for (int s = 0; s < 4; ++s) {
            const int off = (l15 * 256 + 64 * s + 16 * lgrp) ^ ((l15 & 7) << 4);
            hb[s] = *(const short8*)(hbase + off);
        }

        // gates = bias + W_ih@x + W_hh@h, two MFMA chains per tile:
        // chain A (bias -> x -> s0 -> s1) starts before LDS reads return;
        // chain B (s2 -> s3) joins at the end.  Depth 4+2 instead of 5.
        floatx4 accA[4], accB[4];
        #pragma unroll
        for (int tg = 0; tg < 4; ++tg) {
            accA[tg] = (floatx4){bias[tg][0], bias[tg][1], bias[tg][2], bias[tg][3]};
            accA[tg] = __builtin_amdgcn_mfma_f32_16x16x32_bf16(afr[tg][4], xf, accA[tg], 0, 0, 0);
        }
        #pragma unroll
        for (int tg = 0; tg < 4; ++tg)
            accA[tg] = __builtin_amdgcn_mfma_f32_16x16x32_bf16(afr[tg][0], hb[0], accA[tg], 0, 0, 0);
        #pragma unroll
        for (int tg = 0; tg < 4; ++tg)
            accA[tg] = __builtin_amdgcn_mfma_f32_16x16x32_bf16(afr[tg][1], hb[1], accA[tg], 0, 0, 0);
        #pragma unroll
        for (int tg = 0; tg < 4; ++tg) {
            accB[tg] = (floatx4){0.f, 0.f, 0.f, 0.f};
            accB[tg] = __builtin_amdgcn_mfma_f32_16x16x32_bf16(afr[tg][2], hb[2], accB[tg], 0, 0, 0);
            accB[tg] = __builtin_amdgcn_mfma_f32_16x16x32_bf16(afr[tg][3], hb[3], accB[tg], 0, 0, 0);
        }

        // lane-local i/f/g/o quad -> c,h update (b = l15, j = j0 + r)
        #pragma unroll
        for (int r = 0; r < 4; ++r) {
            const float iv = fsig(accA[0][r] + accB[0][r]);
            const float fv = fsig(accA[1][r] + accB[1][r]);
            const float gv = ftanh(accA[2][r] + accB[2][r]);
            const float ov = fsig(accA[3][r] + accB[3][r]);
            const float cn = fv * c[r] + iv * gv;
            c[r]    = cn;
            hreg[r] = ov * ftanh(cn);
        }

        // write h_new (bf16) to the other buffer; one lgkm-only barrier per step
        {
            unsigned u0 = f2bf(hreg[0]) | (f2bf(hreg[1]) << 16);
            unsigned u1 = f2bf(hreg[2]) | (f2bf(hreg[3]) << 16);
            uint2 uv; uv.x = u0; uv.y = u1;
            *(uint2*)((char*)h_lds[cur ^ 1] + wr_off) = uv;
        }
        step_barrier();
        cur ^= 1;
    }

    // ---- epilogue: h_n, c_n, q = h @ fc_w^T + fc_b ----
    {
        floatx4 hv = {hreg[0], hreg[1], hreg[2], hreg[3]};
        floatx4 cv = {c[0], c[1], c[2], c[3]};
        *(floatx4*)(out + 10240 + bglob * HH + j0)          = hv;  // h_n
        *(floatx4*)(out + 10240 + 131072 + bglob * HH + j0) = cv;  // c_n
        hq[l15][j0 + 0] = hreg[0]; hq[l15][j0 + 1] = hreg[1];
        hq[l15][j0 + 2] = hreg[2]; hq[l15][j0 + 3] = hreg[3];
    }
    __syncthreads();
    if (tid < 16 * AA) {
        const int b = tid / AA, a = tid - AA * b;
        float s = fc_b[a];
        const float* fw = fc_w + a * HH;
        const float* hr = &hq[b][0];
        #pragma unroll 8
        for (int j = 0; j < HH; ++j) s = fmaf(hr[j], fw[j], s);
        out[((long)blockIdx.x * 16 + b) * AA + a] = s;
    }
}

extern "C" void kernel_launch(void* const* d_in, const int* in_sizes, int n_in,
                              void* d_out, int out_size, void* d_ws, size_t ws_size,
                              hipStream_t stream) {
    const float* x    = (const float*)d_in[0];
    const float* W_ih = (const float*)d_in[1];
    const float* W_hh = (const float*)d_in[2];
    const float* b_ih = (const float*)d_in[3];
    const float* b_hh = (const float*)d_in[4];
    const float* fc_w = (const float*)d_in[5];
    const float* fc_b = (const float*)d_in[6];
    lstm_fused<<<dim3(1024 / 16), dim3(512), 0, stream>>>(
        x, W_ih, W_hh, b_ih, b_hh, fc_w, fc_b, (float*)d_out);
}

// Round 3
// 414.286 us; speedup vs baseline: 1.1537x; 1.1246x over previous
//
#include <hip/hip_runtime.h>

typedef short  short8  __attribute__((ext_vector_type(8)));
typedef float  floatx4 __attribute__((ext_vector_type(4)));

#define TT 512
#define DD 32
#define HH 128
#define AA 10

__device__ __forceinline__ unsigned f2bf(float f) {
    unsigned u = __builtin_bit_cast(unsigned, f);
    return (u + 0x7fffu + ((u >> 16) & 1u)) >> 16;   // RNE f32 -> bf16
}

__device__ __forceinline__ short8 cvt8(floatx4 a, floatx4 b) {
    short8 r;
    r[0] = (short)f2bf(a[0]); r[1] = (short)f2bf(a[1]);
    r[2] = (short)f2bf(a[2]); r[3] = (short)f2bf(a[3]);
    r[4] = (short)f2bf(b[0]); r[5] = (short)f2bf(b[1]);
    r[6] = (short)f2bf(b[2]); r[7] = (short)f2bf(b[3]);
    return r;
}

__device__ __forceinline__ float fsig(float x) {
    return __builtin_amdgcn_rcpf(1.0f + __expf(-x));
}
__device__ __forceinline__ float ftanh(float x) {
    return 1.0f - 2.0f * __builtin_amdgcn_rcpf(1.0f + __expf(2.0f * x));
}

// Step barrier WITHOUT the vmcnt(0) drain __syncthreads() would emit:
// x prefetch loads float across it (consumed a full step later).
__device__ __forceinline__ void step_barrier() {
    asm volatile("s_waitcnt lgkmcnt(0)" ::: "memory");
    __builtin_amdgcn_s_barrier();
    asm volatile("" ::: "memory");
}

// One block = 4 batch rows; 256 blocks = 1 per CU.
// gates^T = [W_hh | W_ih] @ [h ; x]^T  (M=512 gates, K=160; B cols 4..15 are
// duplicates of cols 0..3 -- MFMA waste is free at 7% MfmaUtil).
// After the MFMA, gates are shuffled through LDS (same-wave, no barrier) so
// ALL 64 lanes process exactly one (b,j) i/f/g/o quad: transcendental issue
// per wave drops 4x (40 -> 10 trans instrs/step).
__global__ __launch_bounds__(512, 2)
void lstm_fused(const float* __restrict__ x,    const float* __restrict__ W_ih,
                const float* __restrict__ W_hh, const float* __restrict__ b_ih,
                const float* __restrict__ b_hh, const float* __restrict__ fc_w,
                const float* __restrict__ fc_b, float* __restrict__ out)
{
    __shared__ unsigned short h_lds[2][4 * HH];    // bf16 h, ^(b<<4) swizzle, dbuf
    __shared__ float gshuf[8][4][4][16];           // [wave][gate][b][jj]  8 KiB
    __shared__ float hq[4][HH + 4];                // final h (f32) for fc epilogue

    const int tid  = threadIdx.x;
    const int lane = tid & 63;
    const int w    = tid >> 6;      // wave 0..7
    const int l15  = lane & 15;     // A-row within tile / B-col / D-col
    const int lgrp = lane >> 4;     // k-group 0..3
    const int bloc = l15 & 3;       // batch row this lane loads (cols duplicated)

    const long bglob = (long)blockIdx.x * 4 + bloc;

    // ---- resident A-fragments of [W_hh | W_ih] (bf16) + bias ----
    // wave w owns tiles {w, w+8, w+16, w+24} = i/f/g/o rows for j in [16w,16w+16)
    short8 afr[4][5];
    float  bias[4][4];
    #pragma unroll
    for (int tg = 0; tg < 4; ++tg) {
        const int m  = w + 8 * tg;
        const int ga = 16 * m + l15;                 // A-frag gate row for this lane
        #pragma unroll
        for (int s = 0; s < 4; ++s) {                // K slices 0..127 -> W_hh
            const float* p = W_hh + ga * HH + 32 * s + 8 * lgrp;
            afr[tg][s] = cvt8(*(const floatx4*)p, *(const floatx4*)(p + 4));
        }
        {                                            // K slice 128..159 -> W_ih
            const float* p = W_ih + ga * DD + 8 * lgrp;
            afr[tg][4] = cvt8(*(const floatx4*)p, *(const floatx4*)(p + 4));
        }
        #pragma unroll
        for (int r = 0; r < 4; ++r) {                // D row = 4*lgrp + r
            const int gd = 16 * m + 4 * lgrp + r;
            bias[tg][r] = b_ih[gd] + b_hh[gd];
        }
    }

    // zero both h buffers (h0 = 0): 2 * 512 ushort = 256 uints
    for (int i = tid; i < 4 * HH; i += 512) ((unsigned*)h_lds)[i & (4 * HH - 1)] = 0u;
    if (tid < 256) ((unsigned*)h_lds)[tid] = 0u;  // (both halves; simple & safe)
    __syncthreads();

    // x prefetch for t=0
    floatx4 xa = *(const floatx4*)(x + (bglob * TT) * DD + 8 * lgrp);
    floatx4 xb = *(const floatx4*)(x + (bglob * TT) * DD + 8 * lgrp + 4);

    // packed-lane assignment for the elementwise phase: one (b,j) per lane
    const int bp = lane & 3;          // batch row of this lane's h/c value
    const int jj = lane >> 2;         // 0..15
    const int jp = 16 * w + jj;       // global j
    float cval = 0.f, hval = 0.f;
    const int hwr_off = (bp * 256 + 2 * jp) ^ (bp << 4);   // swizzled h write addr

    int cur = 0;
    for (int t = 0; t < TT; ++t) {
        short8 xf = cvt8(xa, xb);
        {   // prefetch next step's x (never drained at the step barrier)
            const int tn = (t + 1 < TT) ? (t + 1) : (TT - 1);
            const float* xp = x + (bglob * TT + tn) * DD + 8 * lgrp;
            xa = *(const floatx4*)(xp);
            xb = *(const floatx4*)(xp + 4);
        }

        // h B-frags from LDS: lane needs h[bloc][32s + 8*lgrp .. +7]
        short8 hb[4];
        const char* hbase = (const char*)h_lds[cur];
        #pragma unroll
        for (int s = 0; s < 4; ++s) {
            const int off = (bloc * 256 + 64 * s + 16 * lgrp) ^ (bloc << 4);
            hb[s] = *(const short8*)(hbase + off);
        }

        // gates = bias + W_ih@x + W_hh@h, two MFMA chains per tile
        floatx4 accA[4], accB[4];
        #pragma unroll
        for (int tg = 0; tg < 4; ++tg) {
            accA[tg] = (floatx4){bias[tg][0], bias[tg][1], bias[tg][2], bias[tg][3]};
            accA[tg] = __builtin_amdgcn_mfma_f32_16x16x32_bf16(afr[tg][4], xf, accA[tg], 0, 0, 0);
        }
        #pragma unroll
        for (int tg = 0; tg < 4; ++tg)
            accA[tg] = __builtin_amdgcn_mfma_f32_16x16x32_bf16(afr[tg][0], hb[0], accA[tg], 0, 0, 0);
        #pragma unroll
        for (int tg = 0; tg < 4; ++tg)
            accA[tg] = __builtin_amdgcn_mfma_f32_16x16x32_bf16(afr[tg][1], hb[1], accA[tg], 0, 0, 0);
        #pragma unroll
        for (int tg = 0; tg < 4; ++tg) {
            accB[tg] = (floatx4){0.f, 0.f, 0.f, 0.f};
            accB[tg] = __builtin_amdgcn_mfma_f32_16x16x32_bf16(afr[tg][2], hb[2], accB[tg], 0, 0, 0);
            accB[tg] = __builtin_amdgcn_mfma_f32_16x16x32_bf16(afr[tg][3], hb[3], accB[tg], 0, 0, 0);
        }

        // ship valid gate columns (b = l15 < 4) through LDS; same-wave only
        if (l15 < 4) {
            #pragma unroll
            for (int tg = 0; tg < 4; ++tg) {
                floatx4 v = accA[tg] + accB[tg];
                *(floatx4*)&gshuf[w][tg][l15][4 * lgrp] = v;
            }
        }
        asm volatile("s_waitcnt lgkmcnt(0)" ::: "memory");

        // every lane: one (bp, jp) quad
        const float gi = gshuf[w][0][bp][jj];
        const float gf = gshuf[w][1][bp][jj];
        const float gg = gshuf[w][2][bp][jj];
        const float go = gshuf[w][3][bp][jj];

        const float iv = fsig(gi);
        const float fv = fsig(gf);
        const float gv = ftanh(gg);
        const float ov = fsig(go);
        cval = fv * cval + iv * gv;
        hval = ov * ftanh(cval);

        // write h (bf16) to the other buffer; one lgkm-only barrier per step
        *(unsigned short*)((char*)h_lds[cur ^ 1] + hwr_off) = (unsigned short)f2bf(hval);
        step_barrier();
        cur ^= 1;
    }

    // ---- epilogue: h_n, c_n, q = h @ fc_w^T + fc_b ----
    {
        const long bg = (long)blockIdx.x * 4 + bp;
        out[10240 + bg * HH + jp]          = hval;   // h_n
        out[10240 + 131072 + bg * HH + jp] = cval;   // c_n
        hq[bp][jp] = hval;
    }
    __syncthreads();
    if (tid < 4 * AA) {
        const int b = tid / AA, a = tid - AA * b;
        float s = fc_b[a];
        const float* fw = fc_w + a * HH;
        const float* hr = &hq[b][0];
        #pragma unroll 8
        for (int j = 0; j < HH; ++j) s = fmaf(hr[j], fw[j], s);
        out[((long)blockIdx.x * 4 + b) * AA + a] = s;
    }
}

extern "C" void kernel_launch(void* const* d_in, const int* in_sizes, int n_in,
                              void* d_out, int out_size, void* d_ws, size_t ws_size,
                              hipStream_t stream) {
    const float* x    = (const float*)d_in[0];
    const float* W_ih = (const float*)d_in[1];
    const float* W_hh = (const float*)d_in[2];
    const float* b_ih = (const float*)d_in[3];
    const float* b_hh = (const float*)d_in[4];
    const float* fc_w = (const float*)d_in[5];
    const float* fc_b = (const float*)d_in[6];
    lstm_fused<<<dim3(1024 / 4), dim3(512), 0, stream>>>(
        x, W_ih, W_hh, b_ih, b_hh, fc_w, fc_b, (float*)d_out);
}

// Round 4
// 399.872 us; speedup vs baseline: 1.1953x; 1.0360x over previous
//
#include <hip/hip_runtime.h>

typedef short  short8  __attribute__((ext_vector_type(8)));
typedef float  floatx4 __attribute__((ext_vector_type(4)));

#define TT 512
#define DD 32
#define HH 128
#define AA 10

__device__ __forceinline__ unsigned f2bf(float f) {
    unsigned u = __builtin_bit_cast(unsigned, f);
    return (u + 0x7fffu + ((u >> 16) & 1u)) >> 16;   // RNE f32 -> bf16
}

__device__ __forceinline__ short8 cvt8(floatx4 a, floatx4 b) {
    short8 r;
    r[0] = (short)f2bf(a[0]); r[1] = (short)f2bf(a[1]);
    r[2] = (short)f2bf(a[2]); r[3] = (short)f2bf(a[3]);
    r[4] = (short)f2bf(b[0]); r[5] = (short)f2bf(b[1]);
    r[6] = (short)f2bf(b[2]); r[7] = (short)f2bf(b[3]);
    return r;
}

__device__ __forceinline__ float fsig(float x) {
    return __builtin_amdgcn_rcpf(1.0f + __expf(-x));
}
__device__ __forceinline__ float ftanh(float x) {
    return 1.0f - 2.0f * __builtin_amdgcn_rcpf(1.0f + __expf(2.0f * x));
}

__device__ __forceinline__ void step_barrier() {
    asm volatile("s_waitcnt lgkmcnt(0)" ::: "memory");
    __builtin_amdgcn_s_barrier();
    asm volatile("" ::: "memory");
}

// Prepass: x (f32) -> bf16 in d_ws, same [B][T][D] layout. 16.78M elems,
// one short8 per thread, exact grid (8192*256*8 == 1024*512*32).
__global__ __launch_bounds__(256)
void xcvt(const float* __restrict__ x, unsigned short* __restrict__ xb) {
    const long i = (long)blockIdx.x * 256 + threadIdx.x;
    floatx4 a = *(const floatx4*)(x + 8 * i);
    floatx4 b = *(const floatx4*)(x + 8 * i + 4);
    *(short8*)(xb + 8 * i) = cvt8(a, b);
}

// One block = 4 batch rows; 256 blocks = 1 per CU.
// gates^T = [W_hh | W_ih] @ [h ; x]^T, weights resident in VGPRs.
// Post-MFMA gate shuffle through LDS (same-wave) packs the elementwise to
// one (b,j) quad per lane.
template<int USEWS>
__global__ __launch_bounds__(512, 2)
void lstm_fused(const float* __restrict__ x,    const unsigned short* __restrict__ xbf,
                const float* __restrict__ W_ih, const float* __restrict__ W_hh,
                const float* __restrict__ b_ih, const float* __restrict__ b_hh,
                const float* __restrict__ fc_w, const float* __restrict__ fc_b,
                float* __restrict__ out)
{
    __shared__ unsigned short h_lds[2][4 * HH];    // bf16 h, ^((b&1)<<6) swizzle, dbuf
    __shared__ float gshuf[8][4][4][16];           // [wave][gate][b][jj]
    __shared__ float hq[4][HH + 4];                // final h (f32) for fc epilogue

    const int tid  = threadIdx.x;
    const int lane = tid & 63;
    const int w    = tid >> 6;      // wave 0..7
    const int l15  = lane & 15;
    const int lgrp = lane >> 4;     // k-group 0..3
    const int bloc = l15 & 3;       // batch row this lane's B-frag covers

    const long bglob = (long)blockIdx.x * 4 + bloc;

    // ---- resident A-fragments of [W_hh | W_ih] (bf16) + bias as C-operand ----
    short8  afr[4][5];
    floatx4 biasv[4];
    #pragma unroll
    for (int tg = 0; tg < 4; ++tg) {
        const int m  = w + 8 * tg;
        const int ga = 16 * m + l15;
        #pragma unroll
        for (int s = 0; s < 4; ++s) {                // K slices 0..127 -> W_hh
            const float* p = W_hh + ga * HH + 32 * s + 8 * lgrp;
            afr[tg][s] = cvt8(*(const floatx4*)p, *(const floatx4*)(p + 4));
        }
        {                                            // K slice 128..159 -> W_ih
            const float* p = W_ih + ga * DD + 8 * lgrp;
            afr[tg][4] = cvt8(*(const floatx4*)p, *(const floatx4*)(p + 4));
        }
        #pragma unroll
        for (int r = 0; r < 4; ++r) {                // D row = 4*lgrp + r
            const int gd = 16 * m + 4 * lgrp + r;
            biasv[tg][r] = b_ih[gd] + b_hh[gd];
        }
    }
    const floatx4 zf = {0.f, 0.f, 0.f, 0.f};

    // zero both h buffers: exactly 512 dwords
    ((unsigned*)h_lds)[tid] = 0u;
    __syncthreads();

    // x for t=0
    short8  xf;
    floatx4 xa, xb_;
    if constexpr (USEWS) {
        xf = *(const short8*)(xbf + (bglob * TT) * DD + 8 * lgrp);
    } else {
        xa  = *(const floatx4*)(x + (bglob * TT) * DD + 8 * lgrp);
        xb_ = *(const floatx4*)(x + (bglob * TT) * DD + 8 * lgrp + 4);
    }

    // packed-lane assignment for the elementwise phase
    const int bp = lane & 3;
    const int jj = lane >> 2;
    const int jp = 16 * w + jj;
    float cval = 0.f, hval = 0.f;
    const int hwr_off = (bp * 256 + 2 * jp) ^ ((bp & 1) << 6);

    int cur = 0;
    for (int t = 0; t < TT; ++t) {
        short8 xcur;
        const int tn = (t + 1 < TT) ? (t + 1) : (TT - 1);
        if constexpr (USEWS) {
            xcur = xf;
            xf = *(const short8*)(xbf + (bglob * TT + tn) * DD + 8 * lgrp);
        } else {
            xcur = cvt8(xa, xb_);
            const float* xp = x + (bglob * TT + tn) * DD + 8 * lgrp;
            xa  = *(const floatx4*)(xp);
            xb_ = *(const floatx4*)(xp + 4);
        }

        // h B-frags from LDS; rows are 256 B (2 full bank rotations) so the
        // swizzle must flip bank-half: ^((bloc&1)<<6) -> 2-way max (free)
        short8 hb[4];
        const char* hbase = (const char*)h_lds[cur];
        #pragma unroll
        for (int s = 0; s < 4; ++s) {
            const int off = (bloc * 256 + 64 * s + 16 * lgrp) ^ ((bloc & 1) << 6);
            hb[s] = *(const short8*)(hbase + off);
        }

        // two depth-3 MFMA chains per tg; x-MFMA first (no LDS dependency),
        // bias/zero vectors as C-operands (no per-step acc init movs)
        floatx4 accA[4], accB[4];
        #pragma unroll
        for (int tg = 0; tg < 4; ++tg)
            accA[tg] = __builtin_amdgcn_mfma_f32_16x16x32_bf16(afr[tg][4], xcur, biasv[tg], 0, 0, 0);
        #pragma unroll
        for (int tg = 0; tg < 4; ++tg)
            accB[tg] = __builtin_amdgcn_mfma_f32_16x16x32_bf16(afr[tg][0], hb[0], zf, 0, 0, 0);
        #pragma unroll
        for (int tg = 0; tg < 4; ++tg)
            accA[tg] = __builtin_amdgcn_mfma_f32_16x16x32_bf16(afr[tg][1], hb[1], accA[tg], 0, 0, 0);
        #pragma unroll
        for (int tg = 0; tg < 4; ++tg)
            accB[tg] = __builtin_amdgcn_mfma_f32_16x16x32_bf16(afr[tg][2], hb[2], accB[tg], 0, 0, 0);
        #pragma unroll
        for (int tg = 0; tg < 4; ++tg)
            accA[tg] = __builtin_amdgcn_mfma_f32_16x16x32_bf16(afr[tg][3], hb[3], accA[tg], 0, 0, 0);

        // ship valid gate columns through LDS; same-wave only, no barrier
        if (l15 < 4) {
            #pragma unroll
            for (int tg = 0; tg < 4; ++tg) {
                floatx4 v = accA[tg] + accB[tg];
                *(floatx4*)&gshuf[w][tg][l15][4 * lgrp] = v;
            }
        }
        asm volatile("s_waitcnt lgkmcnt(0)" ::: "memory");

        // every lane: one (bp, jp) quad
        const float gi = gshuf[w][0][bp][jj];
        const float gf = gshuf[w][1][bp][jj];
        const float gg = gshuf[w][2][bp][jj];
        const float go = gshuf[w][3][bp][jj];

        const float iv = fsig(gi);
        const float fv = fsig(gf);
        const float gv = ftanh(gg);
        const float ov = fsig(go);
        cval = fv * cval + iv * gv;
        hval = ov * ftanh(cval);

        *(unsigned short*)((char*)h_lds[cur ^ 1] + hwr_off) = (unsigned short)f2bf(hval);
        step_barrier();
        cur ^= 1;
    }

    // ---- epilogue: h_n, c_n, q = h @ fc_w^T + fc_b ----
    {
        const long bg = (long)blockIdx.x * 4 + bp;
        out[10240 + bg * HH + jp]          = hval;   // h_n
        out[10240 + 131072 + bg * HH + jp] = cval;   // c_n
        hq[bp][jp] = hval;
    }
    __syncthreads();
    if (tid < 4 * AA) {
        const int b = tid / AA, a = tid - AA * b;
        float s = fc_b[a];
        const float* fw = fc_w + a * HH;
        const float* hr = &hq[b][0];
        #pragma unroll 8
        for (int j = 0; j < HH; ++j) s = fmaf(hr[j], fw[j], s);
        out[((long)blockIdx.x * 4 + b) * AA + a] = s;
    }
}

extern "C" void kernel_launch(void* const* d_in, const int* in_sizes, int n_in,
                              void* d_out, int out_size, void* d_ws, size_t ws_size,
                              hipStream_t stream) {
    const float* x    = (const float*)d_in[0];
    const float* W_ih = (const float*)d_in[1];
    const float* W_hh = (const float*)d_in[2];
    const float* b_ih = (const float*)d_in[3];
    const float* b_hh = (const float*)d_in[4];
    const float* fc_w = (const float*)d_in[5];
    const float* fc_b = (const float*)d_in[6];
    float* out = (float*)d_out;

    const size_t xelems = (size_t)1024 * TT * DD;       // 16.78M
    if (ws_size >= xelems * sizeof(unsigned short)) {
        unsigned short* xb = (unsigned short*)d_ws;
        xcvt<<<dim3(8192), dim3(256), 0, stream>>>(x, xb);
        lstm_fused<1><<<dim3(256), dim3(512), 0, stream>>>(
            x, xb, W_ih, W_hh, b_ih, b_hh, fc_w, fc_b, out);
    } else {
        lstm_fused<0><<<dim3(256), dim3(512), 0, stream>>>(
            x, nullptr, W_ih, W_hh, b_ih, b_hh, fc_w, fc_b, out);
    }
}

// Round 5
// 323.219 us; speedup vs baseline: 1.4788x; 1.2372x over previous
//
#include <hip/hip_runtime.h>

typedef short  short8  __attribute__((ext_vector_type(8)));
typedef float  floatx4 __attribute__((ext_vector_type(4)));

#define TT 512
#define DD 32
#define HH 128
#define AA 10
#define LOG2E 1.44269504088896340736f

__device__ __forceinline__ unsigned f2bf(float f) {
    unsigned u = __builtin_bit_cast(unsigned, f);
    return (u + 0x7fffu + ((u >> 16) & 1u)) >> 16;   // RNE f32 -> bf16
}

__device__ __forceinline__ short8 cvt8(floatx4 a, floatx4 b) {
    short8 r;
    r[0] = (short)f2bf(a[0]); r[1] = (short)f2bf(a[1]);
    r[2] = (short)f2bf(a[2]); r[3] = (short)f2bf(a[3]);
    r[4] = (short)f2bf(b[0]); r[5] = (short)f2bf(b[1]);
    r[6] = (short)f2bf(b[2]); r[7] = (short)f2bf(b[3]);
    return r;
}

// activations on pre-scaled gates: exp2 directly (scale folded into weights)
__device__ __forceinline__ float sig2(float a) {   // a = -x*log2e
    return __builtin_amdgcn_rcpf(1.0f + __builtin_amdgcn_exp2f(a));
}
__device__ __forceinline__ float tanh2(float a) {  // a = 2x*log2e
    return 1.0f - 2.0f * __builtin_amdgcn_rcpf(1.0f + __builtin_amdgcn_exp2f(a));
}

// Step barrier WITHOUT the vmcnt(0) drain __syncthreads() would emit:
// x prefetch loads float across it (consumed a full step later).
__device__ __forceinline__ void step_barrier() {
    asm volatile("s_waitcnt lgkmcnt(0)" ::: "memory");
    __builtin_amdgcn_s_barrier();
    asm volatile("" ::: "memory");
}

// Prepass: x (f32) -> bf16 in d_ws, same [B][T][D] layout.
__global__ __launch_bounds__(256)
void xcvt(const float* __restrict__ x, unsigned short* __restrict__ xb) {
    const long i = (long)blockIdx.x * 256 + threadIdx.x;
    floatx4 a = *(const floatx4*)(x + 8 * i);
    floatx4 b = *(const floatx4*)(x + 8 * i + 4);
    *(short8*)(xb + 8 * i) = cvt8(a, b);
}

// One block = 4 batch rows; 256 blocks = 1 per CU.
// gates^T = [W_hh | W_ih] @ [h ; x]^T, weights resident in VGPRs, rows
// pre-scaled by -log2e (i,f,o) / +2log2e (g) so activations use raw exp2.
// B cols 4..15 duplicate batch 0..3, so every lane already holds a full
// i/f/g/o quad for (b=l15&3, j=16w+4lgrp+(l15>>2)) -- packed elementwise
// needs only 12 cndmask register selects, NO LDS round-trip (gshuf removed).
template<int USEWS>
__global__ __launch_bounds__(512, 2)
void lstm_fused(const float* __restrict__ x,    const unsigned short* __restrict__ xbf,
                const float* __restrict__ W_ih, const float* __restrict__ W_hh,
                const float* __restrict__ b_ih, const float* __restrict__ b_hh,
                const float* __restrict__ fc_w, const float* __restrict__ fc_b,
                float* __restrict__ out)
{
    __shared__ unsigned short h_lds[2][4 * HH];    // bf16 h, ^((b&1)<<6) swizzle, dbuf
    __shared__ float hq[4][HH + 4];                // final h (f32) for fc epilogue

    const int tid  = threadIdx.x;
    const int lane = tid & 63;
    const int w    = tid >> 6;      // wave 0..7
    const int l15  = lane & 15;
    const int lgrp = lane >> 4;     // k-group 0..3
    const int bloc = l15 & 3;       // batch row this lane's B-frag covers

    const long bglob = (long)blockIdx.x * 4 + bloc;

    // ---- resident A-fragments of [W_hh | W_ih] (bf16, gate-scaled) ----
    short8  afr[4][5];
    floatx4 biasv[4];
    #pragma unroll
    for (int tg = 0; tg < 4; ++tg) {
        const float sc = (tg == 2) ? (2.0f * LOG2E) : (-LOG2E);
        const int m  = w + 8 * tg;
        const int ga = 16 * m + l15;
        #pragma unroll
        for (int s = 0; s < 4; ++s) {                // K slices 0..127 -> W_hh
            const float* p = W_hh + ga * HH + 32 * s + 8 * lgrp;
            afr[tg][s] = cvt8(*(const floatx4*)p * sc, *(const floatx4*)(p + 4) * sc);
        }
        {                                            // K slice 128..159 -> W_ih
            const float* p = W_ih + ga * DD + 8 * lgrp;
            afr[tg][4] = cvt8(*(const floatx4*)p * sc, *(const floatx4*)(p + 4) * sc);
        }
        #pragma unroll
        for (int r = 0; r < 4; ++r) {                // D row = 4*lgrp + r
            const int gd = 16 * m + 4 * lgrp + r;
            biasv[tg][r] = (b_ih[gd] + b_hh[gd]) * sc;
        }
    }
    const floatx4 zf = {0.f, 0.f, 0.f, 0.f};

    // zero both h buffers: exactly 512 dwords
    ((unsigned*)h_lds)[tid] = 0u;
    __syncthreads();

    // x for t=0
    short8  xf;
    floatx4 xa, xb_;
    if constexpr (USEWS) {
        xf = *(const short8*)(xbf + (bglob * TT) * DD + 8 * lgrp);
    } else {
        xa  = *(const floatx4*)(x + (bglob * TT) * DD + 8 * lgrp);
        xb_ = *(const floatx4*)(x + (bglob * TT) * DD + 8 * lgrp + 4);
    }

    // packed-lane assignment: reg-select rs = l15>>2, one (b,j) quad per lane
    const int rs  = l15 >> 2;
    const bool sb0 = (rs & 1) != 0;
    const bool sb1 = (rs & 2) != 0;
    const int bp  = bloc;
    const int jp  = 16 * w + 4 * lgrp + rs;
    float cval = 0.f, hval = 0.f;
    const int hwr_off = (bp * 256 + 2 * jp) ^ ((bp & 1) << 6);

    int cur = 0;
    for (int t = 0; t < TT; ++t) {
        short8 xcur;
        const int tn = (t + 1 < TT) ? (t + 1) : (TT - 1);
        if constexpr (USEWS) {
            xcur = xf;
            xf = *(const short8*)(xbf + (bglob * TT + tn) * DD + 8 * lgrp);
        } else {
            xcur = cvt8(xa, xb_);
            const float* xp = x + (bglob * TT + tn) * DD + 8 * lgrp;
            xa  = *(const floatx4*)(xp);
            xb_ = *(const floatx4*)(xp + 4);
        }

        // h B-frags from LDS: lane needs h[bloc][32s + 8*lgrp .. +7]
        short8 hb[4];
        const char* hbase = (const char*)h_lds[cur];
        #pragma unroll
        for (int s = 0; s < 4; ++s) {
            const int off = (bloc * 256 + 64 * s + 16 * lgrp) ^ ((bloc & 1) << 6);
            hb[s] = *(const short8*)(hbase + off);
        }

        // two depth-3 MFMA chains per tg; x-MFMA first (no LDS dependency)
        floatx4 accA[4], accB[4];
        #pragma unroll
        for (int tg = 0; tg < 4; ++tg)
            accA[tg] = __builtin_amdgcn_mfma_f32_16x16x32_bf16(afr[tg][4], xcur, biasv[tg], 0, 0, 0);
        #pragma unroll
        for (int tg = 0; tg < 4; ++tg)
            accB[tg] = __builtin_amdgcn_mfma_f32_16x16x32_bf16(afr[tg][0], hb[0], zf, 0, 0, 0);
        #pragma unroll
        for (int tg = 0; tg < 4; ++tg)
            accA[tg] = __builtin_amdgcn_mfma_f32_16x16x32_bf16(afr[tg][1], hb[1], accA[tg], 0, 0, 0);
        #pragma unroll
        for (int tg = 0; tg < 4; ++tg)
            accB[tg] = __builtin_amdgcn_mfma_f32_16x16x32_bf16(afr[tg][2], hb[2], accB[tg], 0, 0, 0);
        #pragma unroll
        for (int tg = 0; tg < 4; ++tg)
            accA[tg] = __builtin_amdgcn_mfma_f32_16x16x32_bf16(afr[tg][3], hb[3], accA[tg], 0, 0, 0);

        // pack via register select: lane takes quad element rs = l15>>2
        float g4[4];
        #pragma unroll
        for (int tg = 0; tg < 4; ++tg) {
            floatx4 sv = accA[tg] + accB[tg];
            const float v01 = sb0 ? sv[1] : sv[0];
            const float v23 = sb0 ? sv[3] : sv[2];
            g4[tg] = sb1 ? v23 : v01;
        }

        const float iv = sig2(g4[0]);
        const float fv = sig2(g4[1]);
        const float gv = tanh2(g4[2]);
        const float ov = sig2(g4[3]);
        cval = fv * cval + iv * gv;
        hval = ov * tanh2(cval * (2.0f * LOG2E));

        *(unsigned short*)((char*)h_lds[cur ^ 1] + hwr_off) = (unsigned short)f2bf(hval);
        step_barrier();
        cur ^= 1;
    }

    // ---- epilogue: h_n, c_n, q = h @ fc_w^T + fc_b ----
    {
        const long bg = (long)blockIdx.x * 4 + bp;
        out[10240 + bg * HH + jp]          = hval;   // h_n
        out[10240 + 131072 + bg * HH + jp] = cval;   // c_n
        hq[bp][jp] = hval;
    }
    __syncthreads();
    if (tid < 4 * AA) {
        const int b = tid / AA, a = tid - AA * b;
        float s = fc_b[a];
        const float* fw = fc_w + a * HH;
        const float* hr = &hq[b][0];
        #pragma unroll 8
        for (int j = 0; j < HH; ++j) s = fmaf(hr[j], fw[j], s);
        out[((long)blockIdx.x * 4 + b) * AA + a] = s;
    }
}

extern "C" void kernel_launch(void* const* d_in, const int* in_sizes, int n_in,
                              void* d_out, int out_size, void* d_ws, size_t ws_size,
                              hipStream_t stream) {
    const float* x    = (const float*)d_in[0];
    const float* W_ih = (const float*)d_in[1];
    const float* W_hh = (const float*)d_in[2];
    const float* b_ih = (const float*)d_in[3];
    const float* b_hh = (const float*)d_in[4];
    const float* fc_w = (const float*)d_in[5];
    const float* fc_b = (const float*)d_in[6];
    float* out = (float*)d_out;

    const size_t xelems = (size_t)1024 * TT * DD;       // 16.78M
    if (ws_size >= xelems * sizeof(unsigned short)) {
        unsigned short* xb = (unsigned short*)d_ws;
        xcvt<<<dim3(8192), dim3(256), 0, stream>>>(x, xb);
        lstm_fused<1><<<dim3(256), dim3(512), 0, stream>>>(
            x, xb, W_ih, W_hh, b_ih, b_hh, fc_w, fc_b, out);
    } else {
        lstm_fused<0><<<dim3(256), dim3(512), 0, stream>>>(
            x, nullptr, W_ih, W_hh, b_ih, b_hh, fc_w, fc_b, out);
    }
}

// Round 6
// 299.612 us; speedup vs baseline: 1.5953x; 1.0788x over previous
//
#include <hip/hip_runtime.h>

typedef short  short8  __attribute__((ext_vector_type(8)));
typedef float  floatx4 __attribute__((ext_vector_type(4)));

#define TT 512
#define DD 32
#define HH 128
#define AA 10
#define LOG2E 1.44269504088896340736f

__device__ __forceinline__ unsigned f2bf(float f) {
    unsigned u = __builtin_bit_cast(unsigned, f);
    return (u + 0x7fffu + ((u >> 16) & 1u)) >> 16;   // RNE f32 -> bf16
}

__device__ __forceinline__ short8 cvt8(floatx4 a, floatx4 b) {
    short8 r;
    r[0] = (short)f2bf(a[0]); r[1] = (short)f2bf(a[1]);
    r[2] = (short)f2bf(a[2]); r[3] = (short)f2bf(a[3]);
    r[4] = (short)f2bf(b[0]); r[5] = (short)f2bf(b[1]);
    r[6] = (short)f2bf(b[2]); r[7] = (short)f2bf(b[3]);
    return r;
}

// activations on pre-scaled gates (scale folded into weights/bias)
__device__ __forceinline__ float sig2(float a) {   // a = -x*log2e
    return __builtin_amdgcn_rcpf(1.0f + __builtin_amdgcn_exp2f(a));
}
__device__ __forceinline__ float tanh2(float a) {  // a = 2x*log2e
    return 1.0f - 2.0f * __builtin_amdgcn_rcpf(1.0f + __builtin_amdgcn_exp2f(a));
}

// lgkm-only step barrier: x prefetch loads float across it
__device__ __forceinline__ void step_barrier() {
    asm volatile("s_waitcnt lgkmcnt(0)" ::: "memory");
    __builtin_amdgcn_s_barrier();
    asm volatile("" ::: "memory");
}

// Prepass: x (f32) -> bf16 in d_ws, same [B][T][D] layout.
__global__ __launch_bounds__(256)
void xcvt(const float* __restrict__ x, unsigned short* __restrict__ xb) {
    const long i = (long)blockIdx.x * 256 + threadIdx.x;
    floatx4 a = *(const floatx4*)(x + 8 * i);
    floatx4 b = *(const floatx4*)(x + 8 * i + 4);
    *(short8*)(xb + 8 * i) = cvt8(a, b);
}

// One block = 4 batch rows; 256 blocks = 1 per CU.
// gates^T = [W_hh | W_ih] @ [h ; x]^T, weights resident (AGPR), rows
// pre-scaled by -log2e (i,f,o) / +2log2e (g) so activations use raw exp2.
// Lane already holds its full i/f/g/o quad (duplicate-column trick):
// pack = 12 cndmask, no LDS round-trip.
// h layout: addr(b,j) = b*256 + ((2j + 32b) & 255)  -- rotation swizzle,
// conflict-free writes (all 32 banks, 2-way dword-paired) and 2-way reads.
// All LDS offsets hoisted; t-loop unrolled x2 with named offset sets.
template<int USEWS>
__global__ __launch_bounds__(512, 2)
void lstm_fused(const float* __restrict__ x,    const unsigned short* __restrict__ xbf,
                const float* __restrict__ W_ih, const float* __restrict__ W_hh,
                const float* __restrict__ b_ih, const float* __restrict__ b_hh,
                const float* __restrict__ fc_w, const float* __restrict__ fc_b,
                float* __restrict__ out)
{
    __shared__ unsigned short h_lds[2][4 * HH];    // 2 KiB total, dbuf
    __shared__ float hq[4][HH + 4];

    const int tid  = threadIdx.x;
    const int lane = tid & 63;
    const int w    = tid >> 6;
    const int l15  = lane & 15;
    const int lgrp = lane >> 4;     // k-group 0..3
    const int bloc = l15 & 3;       // batch row of this lane's B-frag

    const long bglob = (long)blockIdx.x * 4 + bloc;

    // ---- resident A-fragments (bf16, gate-scaled) + bias C-operands ----
    short8  afr[4][5];
    floatx4 biasv[4];
    #pragma unroll
    for (int tg = 0; tg < 4; ++tg) {
        const float sc = (tg == 2) ? (2.0f * LOG2E) : (-LOG2E);
        const int m  = w + 8 * tg;
        const int ga = 16 * m + l15;
        #pragma unroll
        for (int s = 0; s < 4; ++s) {
            const float* p = W_hh + ga * HH + 32 * s + 8 * lgrp;
            afr[tg][s] = cvt8(*(const floatx4*)p * sc, *(const floatx4*)(p + 4) * sc);
        }
        {
            const float* p = W_ih + ga * DD + 8 * lgrp;
            afr[tg][4] = cvt8(*(const floatx4*)p * sc, *(const floatx4*)(p + 4) * sc);
        }
        #pragma unroll
        for (int r = 0; r < 4; ++r) {
            const int gd = 16 * m + 4 * lgrp + r;
            biasv[tg][r] = (b_ih[gd] + b_hh[gd]) * sc;
        }
    }

    // zero both h buffers: exactly 512 dwords
    ((unsigned*)h_lds)[tid] = 0u;
    __syncthreads();

    // packed-lane mapping: quad element rs = l15>>2
    const int rs  = l15 >> 2;
    const bool sb0 = (rs & 1) != 0;
    const bool sb1 = (rs & 2) != 0;
    const int bp  = bloc;
    const int jp  = 16 * w + 4 * lgrp + rs;

    // hoisted LDS offsets (rotation swizzle), named per buffer
    int rdA0, rdA1, rdA2, rdA3, rdB0, rdB1, rdB2, rdB3;
    {
        const int rb = bloc * 256;
        rdA0 = rb + ((64 * 0 + 16 * lgrp + 32 * bloc) & 255);
        rdA1 = rb + ((64 * 1 + 16 * lgrp + 32 * bloc) & 255);
        rdA2 = rb + ((64 * 2 + 16 * lgrp + 32 * bloc) & 255);
        rdA3 = rb + ((64 * 3 + 16 * lgrp + 32 * bloc) & 255);
        rdB0 = rdA0 + 1024; rdB1 = rdA1 + 1024; rdB2 = rdA2 + 1024; rdB3 = rdA3 + 1024;
    }
    const int wrA = bp * 256 + ((2 * jp + 32 * bp) & 255);          // write into buf0
    const int wrB = wrA + 1024;                                      // write into buf1

    // x for t=0
    short8  xf;
    floatx4 xa, xb_;
    if constexpr (USEWS) {
        xf = *(const short8*)(xbf + (bglob * TT) * DD + 8 * lgrp);
    } else {
        xa  = *(const floatx4*)(x + (bglob * TT) * DD + 8 * lgrp);
        xb_ = *(const floatx4*)(x + (bglob * TT) * DD + 8 * lgrp + 4);
    }

    float cval = 0.f, hval = 0.f;
    const char* lbase = (const char*)h_lds;

    auto STEP = [&](int r0, int r1, int r2, int r3, int wro, int t) {
        short8 xcur;
        const int tn = (t + 1 < TT) ? (t + 1) : (TT - 1);   // uniform (SALU)
        if constexpr (USEWS) {
            xcur = xf;
            xf = *(const short8*)(xbf + (bglob * TT + tn) * DD + 8 * lgrp);
        } else {
            xcur = cvt8(xa, xb_);
            const float* xp = x + (bglob * TT + tn) * DD + 8 * lgrp;
            xa  = *(const floatx4*)(xp);
            xb_ = *(const floatx4*)(xp + 4);
        }

        short8 hb0 = *(const short8*)(lbase + r0);
        short8 hb1 = *(const short8*)(lbase + r1);
        short8 hb2 = *(const short8*)(lbase + r2);
        short8 hb3 = *(const short8*)(lbase + r3);

        // one depth-5 chain per tg, 4 independent chains
        floatx4 acc[4];
        #pragma unroll
        for (int tg = 0; tg < 4; ++tg)
            acc[tg] = __builtin_amdgcn_mfma_f32_16x16x32_bf16(afr[tg][4], xcur, biasv[tg], 0, 0, 0);
        #pragma unroll
        for (int tg = 0; tg < 4; ++tg)
            acc[tg] = __builtin_amdgcn_mfma_f32_16x16x32_bf16(afr[tg][0], hb0, acc[tg], 0, 0, 0);
        #pragma unroll
        for (int tg = 0; tg < 4; ++tg)
            acc[tg] = __builtin_amdgcn_mfma_f32_16x16x32_bf16(afr[tg][1], hb1, acc[tg], 0, 0, 0);
        #pragma unroll
        for (int tg = 0; tg < 4; ++tg)
            acc[tg] = __builtin_amdgcn_mfma_f32_16x16x32_bf16(afr[tg][2], hb2, acc[tg], 0, 0, 0);
        #pragma unroll
        for (int tg = 0; tg < 4; ++tg)
            acc[tg] = __builtin_amdgcn_mfma_f32_16x16x32_bf16(afr[tg][3], hb3, acc[tg], 0, 0, 0);

        // pack via register select (rs = l15>>2)
        float g4[4];
        #pragma unroll
        for (int tg = 0; tg < 4; ++tg) {
            const float v01 = sb0 ? acc[tg][1] : acc[tg][0];
            const float v23 = sb0 ? acc[tg][3] : acc[tg][2];
            g4[tg] = sb1 ? v23 : v01;
        }

        const float iv = sig2(g4[0]);
        const float fv = sig2(g4[1]);
        const float gv = tanh2(g4[2]);
        const float ov = sig2(g4[3]);
        cval = fv * cval + iv * gv;
        hval = ov * tanh2(cval * (2.0f * LOG2E));

        *(unsigned short*)((char*)h_lds + wro) = (unsigned short)f2bf(hval);
        step_barrier();
    };

    #pragma unroll 1
    for (int t = 0; t < TT; t += 2) {
        STEP(rdA0, rdA1, rdA2, rdA3, wrB, t);       // read buf0, write buf1
        STEP(rdB0, rdB1, rdB2, rdB3, wrA, t + 1);   // read buf1, write buf0
    }

    // ---- epilogue: h_n, c_n, q = h @ fc_w^T + fc_b ----
    {
        const long bg = (long)blockIdx.x * 4 + bp;
        out[10240 + bg * HH + jp]          = hval;   // h_n
        out[10240 + 131072 + bg * HH + jp] = cval;   // c_n
        hq[bp][jp] = hval;
    }
    __syncthreads();
    if (tid < 4 * AA) {
        const int b = tid / AA, a = tid - AA * b;
        float s = fc_b[a];
        const float* fw = fc_w + a * HH;
        const float* hr = &hq[b][0];
        #pragma unroll 8
        for (int j = 0; j < HH; ++j) s = fmaf(hr[j], fw[j], s);
        out[((long)blockIdx.x * 4 + b) * AA + a] = s;
    }
}

extern "C" void kernel_launch(void* const* d_in, const int* in_sizes, int n_in,
                              void* d_out, int out_size, void* d_ws, size_t ws_size,
                              hipStream_t stream) {
    const float* x    = (const float*)d_in[0];
    const float* W_ih = (const float*)d_in[1];
    const float* W_hh = (const float*)d_in[2];
    const float* b_ih = (const float*)d_in[3];
    const float* b_hh = (const float*)d_in[4];
    const float* fc_w = (const float*)d_in[5];
    const float* fc_b = (const float*)d_in[6];
    float* out = (float*)d_out;

    const size_t xelems = (size_t)1024 * TT * DD;       // 16.78M
    if (ws_size >= xelems * sizeof(unsigned short)) {
        unsigned short* xb = (unsigned short*)d_ws;
        xcvt<<<dim3(8192), dim3(256), 0, stream>>>(x, xb);
        lstm_fused<1><<<dim3(256), dim3(512), 0, stream>>>(
            x, xb, W_ih, W_hh, b_ih, b_hh, fc_w, fc_b, out);
    } else {
        lstm_fused<0><<<dim3(256), dim3(512), 0, stream>>>(
            x, nullptr, W_ih, W_hh, b_ih, b_hh, fc_w, fc_b, out);
    }
}